// Round 5
// baseline (454.321 us; speedup 1.0000x reference)
//
#include <hip/hip_runtime.h>
#include <math.h>

// Problem constants (B=256, S=512, J=32, D=3)
constexpr int NGROUPS = 256 * 512 * 32;   // 4,194,304 (b,s,j) groups
constexpr int BLOCK   = 256;              // 1 group per thread
constexpr int GRID    = NGROUPS / BLOCK;  // 16384 blocks, exact fit

#define LOG_2PI 1.8378770664093453f

typedef float f32x4 __attribute__((ext_vector_type(4)));

__device__ __forceinline__ float fast_rcp(float x) {
    return __builtin_amdgcn_rcpf(x);
}

// Fused: main pass + deterministic last-block final reduction.
// d_ws layout: [0,4)   unsigned counter (reset to 0 each call via memsetAsync)
//              [256, 256 + GRID*4)  float partials
__global__ __launch_bounds__(BLOCK) void nll_fused(
    const float* __restrict__ yt,
    const float* __restrict__ yp,
    const float* __restrict__ Lm,
    float* __restrict__ partial,
    unsigned int* __restrict__ counter,
    float* __restrict__ out)
{
    __shared__ float syt[768];
    __shared__ float syp[768];
    __shared__ float sl[2304];
    __shared__ float sdata[BLOCK / 64];
    __shared__ bool  s_last;

    const f32x4* yt4 = reinterpret_cast<const f32x4*>(yt);
    const f32x4* yp4 = reinterpret_cast<const f32x4*>(yp);
    const f32x4* L4  = reinterpret_cast<const f32x4*>(Lm);
    f32x4* syt4 = reinterpret_cast<f32x4*>(syt);
    f32x4* syp4 = reinterpret_cast<f32x4*>(syp);
    f32x4* sl4  = reinterpret_cast<f32x4*>(sl);

    const int tid = threadIdx.x;
    const int bx  = blockIdx.x;

    // Coalesced staging: lane i <-> 16 consecutive bytes.
    if (tid < 192) {
        syt4[tid] = yt4[bx * 192 + tid];
        syp4[tid] = yp4[bx * 192 + tid];
    }
    sl4[tid]       = L4[bx * 576 + tid];
    sl4[tid + 256] = L4[bx * 576 + 256 + tid];
    if (tid < 64) sl4[tid + 512] = L4[bx * 576 + 512 + tid];
    __syncthreads();

    // Per-group operands from LDS (strides 3 and 9 floats: conflict-free).
    const float d0 = syt[tid * 3 + 0] - syp[tid * 3 + 0];
    const float d1 = syt[tid * 3 + 1] - syp[tid * 3 + 1];
    const float d2 = syt[tid * 3 + 2] - syp[tid * 3 + 2];
    const float L00 = sl[tid * 9 + 0];
    const float L10 = sl[tid * 9 + 3];
    const float L11 = sl[tid * 9 + 4];
    const float L20 = sl[tid * 9 + 6];
    const float L21 = sl[tid * 9 + 7];
    const float L22 = sl[tid * 9 + 8];

    const float r0 = fast_rcp(L00);
    const float r1 = fast_rcp(L11);
    const float r2 = fast_rcp(L22);
    const float x0 = d0 * r0;
    const float x1 = (d1 - L10 * x0) * r1;
    const float x2 = (d2 - L20 * x0 - L21 * x1) * r2;
    const float maha = x0 * x0 + x1 * x1 + x2 * x2;
    // 0.5*logdet == sum(log diag); constant folded into the final write.
    float acc = 0.5f * maha + __logf(L00) + __logf(L11) + __logf(L22);

    // wave shuffle reduce, then per-block sum
    #pragma unroll
    for (int off = 32; off > 0; off >>= 1) acc += __shfl_down(acc, off, 64);
    const int lane = tid & 63;
    const int wid  = tid >> 6;
    if (lane == 0) sdata[wid] = acc;
    __syncthreads();

    if (tid == 0) {
        float s = sdata[0] + sdata[1] + sdata[2] + sdata[3];
        partial[bx] = s;
        __threadfence();                       // release partial before ticket
        unsigned old = atomicAdd(counter, 1u); // device-scope
        s_last = (old == (unsigned)(GRID - 1));
    }
    __syncthreads();
    if (!s_last) return;

    // ---- Last block: deterministic fixed-order reduction of all partials ----
    __threadfence();                           // acquire: see all partials
    const f32x4* p4 = reinterpret_cast<const f32x4*>(partial); // GRID/4 = 4096 vecs
    float acc2 = 0.0f;
    #pragma unroll
    for (int k = 0; k < 16; ++k) {             // 256 threads * 16 = 4096 vecs
        f32x4 v = p4[tid + 256 * k];
        acc2 += v.x + v.y + v.z + v.w;
    }
    #pragma unroll
    for (int off = 32; off > 0; off >>= 1) acc2 += __shfl_down(acc2, off, 64);
    if (lane == 0) sdata[wid] = acc2;
    __syncthreads();
    if (tid == 0) {
        float s = sdata[0] + sdata[1] + sdata[2] + sdata[3];
        // loss = mean(0.5*maha + sum log diag) + 0.5*D*LOG_2PI
        out[0] = s * (1.0f / (float)NGROUPS) + 0.5f * 3.0f * LOG_2PI;
    }
}

extern "C" void kernel_launch(void* const* d_in, const int* in_sizes, int n_in,
                              void* d_out, int out_size, void* d_ws, size_t ws_size,
                              hipStream_t stream)
{
    const float* yt = (const float*)d_in[0];  // y_true        (B,S,J,D)
    const float* yp = (const float*)d_in[1];  // y_pred_mean   (B,S,J,D)
    const float* Lm = (const float*)d_in[2];  // pred_cholesky (B,S,J,D,D)
    float* out      = (float*)d_out;

    unsigned int* counter = (unsigned int*)d_ws;                   // 4 B
    float* partial = (float*)((char*)d_ws + 256);                  // GRID floats

    // Counter must be 0 at the start of every call (d_ws is poisoned once,
    // never re-poisoned; async memset is graph-capturable).
    hipMemsetAsync(counter, 0, sizeof(unsigned int), stream);
    nll_fused<<<GRID, BLOCK, 0, stream>>>(yt, yp, Lm, partial, counter, out);
}

// Round 6
// 224.970 us; speedup vs baseline: 2.0195x; 2.0195x over previous
//
#include <hip/hip_runtime.h>
#include <math.h>

// Problem constants (B=256, S=512, J=32, D=3)
constexpr int NGROUPS = 256 * 512 * 32;   // 4,194,304 (b,s,j) groups
constexpr int BLOCK   = 256;              // 1 group per thread
constexpr int GRID    = NGROUPS / BLOCK;  // 16384 blocks, exact fit

#define LOG_2PI 1.8378770664093453f

typedef float f32x4 __attribute__((ext_vector_type(4)));

__device__ __forceinline__ float fast_rcp(float x) {
    return __builtin_amdgcn_rcpf(x);
}

// Single fused kernel. Per-block sum -> one device-scope float atomicAdd into
// out[0] (pre-scaled by 1/NGROUPS, constant term folded per-group). Atomics
// execute at the coherence point -- NO fences needed (R5's __threadfence()
// last-block pattern cost 10x: device fences writeback/invalidate the
// non-coherent per-XCD L2s).
__global__ __launch_bounds__(BLOCK) void nll_fused(
    const float* __restrict__ yt,
    const float* __restrict__ yp,
    const float* __restrict__ Lm,
    float* __restrict__ out)
{
    __shared__ float syt[768];
    __shared__ float syp[768];
    __shared__ float sl[2304];
    __shared__ float sdata[BLOCK / 64];

    const f32x4* yt4 = reinterpret_cast<const f32x4*>(yt);
    const f32x4* yp4 = reinterpret_cast<const f32x4*>(yp);
    const f32x4* L4  = reinterpret_cast<const f32x4*>(Lm);
    f32x4* syt4 = reinterpret_cast<f32x4*>(syt);
    f32x4* syp4 = reinterpret_cast<f32x4*>(syp);
    f32x4* sl4  = reinterpret_cast<f32x4*>(sl);

    const int tid = threadIdx.x;
    const int bx  = blockIdx.x;

    // Coalesced staging: lane i <-> 16 consecutive bytes.
    if (tid < 192) {
        syt4[tid] = yt4[bx * 192 + tid];
        syp4[tid] = yp4[bx * 192 + tid];
    }
    sl4[tid]       = L4[bx * 576 + tid];
    sl4[tid + 256] = L4[bx * 576 + 256 + tid];
    if (tid < 64) sl4[tid + 512] = L4[bx * 576 + 512 + tid];
    __syncthreads();

    // Per-group operands from LDS (strides 3 and 9 floats: conflict-free).
    const float d0 = syt[tid * 3 + 0] - syp[tid * 3 + 0];
    const float d1 = syt[tid * 3 + 1] - syp[tid * 3 + 1];
    const float d2 = syt[tid * 3 + 2] - syp[tid * 3 + 2];
    // row-major 3x3: [0]=L00 [3]=L10 [4]=L11 [6]=L20 [7]=L21 [8]=L22
    const float L00 = sl[tid * 9 + 0];
    const float L10 = sl[tid * 9 + 3];
    const float L11 = sl[tid * 9 + 4];
    const float L20 = sl[tid * 9 + 6];
    const float L21 = sl[tid * 9 + 7];
    const float L22 = sl[tid * 9 + 8];

    const float r0 = fast_rcp(L00);
    const float r1 = fast_rcp(L11);
    const float r2 = fast_rcp(L22);
    const float x0 = d0 * r0;
    const float x1 = (d1 - L10 * x0) * r1;
    const float x2 = (d2 - L20 * x0 - L21 * x1) * r2;
    const float maha = x0 * x0 + x1 * x1 + x2 * x2;
    // per-group loss = 0.5*maha + sum(log diag) + 0.5*D*LOG_2PI
    float acc = 0.5f * maha + __logf(L00) + __logf(L11) + __logf(L22)
              + 0.5f * 3.0f * LOG_2PI;

    // wave shuffle reduce, then per-block sum
    #pragma unroll
    for (int off = 32; off > 0; off >>= 1) acc += __shfl_down(acc, off, 64);
    const int lane = tid & 63;
    const int wid  = tid >> 6;
    if (lane == 0) sdata[wid] = acc;
    __syncthreads();

    if (tid == 0) {
        float s = sdata[0] + sdata[1] + sdata[2] + sdata[3];
        // Pre-scale so out accumulates the mean directly.
        atomicAdd(out, s * (1.0f / (float)NGROUPS));
    }
}

extern "C" void kernel_launch(void* const* d_in, const int* in_sizes, int n_in,
                              void* d_out, int out_size, void* d_ws, size_t ws_size,
                              hipStream_t stream)
{
    const float* yt = (const float*)d_in[0];  // y_true        (B,S,J,D)
    const float* yp = (const float*)d_in[1];  // y_pred_mean   (B,S,J,D)
    const float* Lm = (const float*)d_in[2];  // pred_cholesky (B,S,J,D,D)
    float* out      = (float*)d_out;

    // out[0] must start at 0 every call (harness poisons once, not per replay).
    hipMemsetAsync(out, 0, sizeof(float), stream);
    nll_fused<<<GRID, BLOCK, 0, stream>>>(yt, yp, Lm, out);
}

// Round 7
// 43.368 us; speedup vs baseline: 10.4760x; 5.1875x over previous
//
#include <hip/hip_runtime.h>
#include <math.h>

// Problem constants (B=256, S=512, J=32, D=3)
constexpr int NGROUPS = 256 * 512 * 32;   // 4,194,304 (b,s,j) groups
constexpr int BLOCK   = 256;              // 1 group per thread
constexpr int GRID    = NGROUPS / BLOCK;  // 16384 blocks, exact fit

#define LOG_2PI 1.8378770664093453f

typedef float f32x4 __attribute__((ext_vector_type(4)));

__device__ __forceinline__ float fast_rcp(float x) {
    return __builtin_amdgcn_rcpf(x);
}

// R4 structure (proven 44.1 us): coalesced LDS staging + per-block partial
// with plain stores + separate tiny reduce kernel. Fusion attempts measured:
//   R5 __threadfence last-block: 454 us (device fences writeback the 8
//       non-coherent XCD L2s).
//   R6 per-block atomicAdd(out): 225 us (~8 ns serialized service per
//       same-address atomic RMW x 16384 blocks = +131 us tail).
// Cross-block aggregation cheaper than the ~4 us second launch does not
// exist on this chip for >=2048 participants.
__global__ __launch_bounds__(BLOCK) void nll_main(
    const float* __restrict__ yt,
    const float* __restrict__ yp,
    const float* __restrict__ Lm,
    float* __restrict__ partial)
{
    __shared__ float syt[768];
    __shared__ float syp[768];
    __shared__ float sl[2304];

    const f32x4* yt4 = reinterpret_cast<const f32x4*>(yt);
    const f32x4* yp4 = reinterpret_cast<const f32x4*>(yp);
    const f32x4* L4  = reinterpret_cast<const f32x4*>(Lm);
    f32x4* syt4 = reinterpret_cast<f32x4*>(syt);
    f32x4* syp4 = reinterpret_cast<f32x4*>(syp);
    f32x4* sl4  = reinterpret_cast<f32x4*>(sl);

    const int tid = threadIdx.x;
    const int bx  = blockIdx.x;

    // Coalesced staging: lane i <-> 16 consecutive bytes.
    if (tid < 192) {
        syt4[tid] = yt4[bx * 192 + tid];
        syp4[tid] = yp4[bx * 192 + tid];
    }
    sl4[tid]       = L4[bx * 576 + tid];
    sl4[tid + 256] = L4[bx * 576 + 256 + tid];
    if (tid < 64) sl4[tid + 512] = L4[bx * 576 + 512 + tid];
    __syncthreads();

    // Per-group operands from LDS (strides 3 and 9 floats: conflict-free).
    const float d0 = syt[tid * 3 + 0] - syp[tid * 3 + 0];
    const float d1 = syt[tid * 3 + 1] - syp[tid * 3 + 1];
    const float d2 = syt[tid * 3 + 2] - syp[tid * 3 + 2];
    // row-major 3x3: [0]=L00 [3]=L10 [4]=L11 [6]=L20 [7]=L21 [8]=L22
    const float L00 = sl[tid * 9 + 0];
    const float L10 = sl[tid * 9 + 3];
    const float L11 = sl[tid * 9 + 4];
    const float L20 = sl[tid * 9 + 6];
    const float L21 = sl[tid * 9 + 7];
    const float L22 = sl[tid * 9 + 8];

    const float r0 = fast_rcp(L00);
    const float r1 = fast_rcp(L11);
    const float r2 = fast_rcp(L22);
    const float x0 = d0 * r0;
    const float x1 = (d1 - L10 * x0) * r1;
    const float x2 = (d2 - L20 * x0 - L21 * x1) * r2;
    const float maha = x0 * x0 + x1 * x1 + x2 * x2;
    // 0.5 * logdet == sum(log diag); constant term folded into final reduce.
    float acc = 0.5f * maha + __logf(L00) + __logf(L11) + __logf(L22);

    // wave (64-lane) shuffle reduce
    #pragma unroll
    for (int off = 32; off > 0; off >>= 1) acc += __shfl_down(acc, off, 64);

    __shared__ float sdata[BLOCK / 64];
    const int lane = tid & 63;
    const int wid  = tid >> 6;
    if (lane == 0) sdata[wid] = acc;
    __syncthreads();
    if (tid == 0) {
        float s = 0.0f;
        #pragma unroll
        for (int w = 0; w < BLOCK / 64; ++w) s += sdata[w];
        partial[bx] = s;
    }
}

__global__ __launch_bounds__(1024) void nll_reduce(
    const float* __restrict__ partial, float* __restrict__ out)
{
    // GRID = 16384 partials = 4096 float4
    const f32x4* p4 = reinterpret_cast<const f32x4*>(partial);
    float acc = 0.0f;
    #pragma unroll
    for (int k = 0; k < 4; ++k) {
        f32x4 v = p4[threadIdx.x + k * 1024];
        acc += v.x + v.y + v.z + v.w;
    }

    #pragma unroll
    for (int off = 32; off > 0; off >>= 1) acc += __shfl_down(acc, off, 64);

    __shared__ float sdata[16];
    const int lane = threadIdx.x & 63;
    const int wid  = threadIdx.x >> 6;
    if (lane == 0) sdata[wid] = acc;
    __syncthreads();
    if (threadIdx.x == 0) {
        float s = 0.0f;
        #pragma unroll
        for (int w = 0; w < 16; ++w) s += sdata[w];
        // loss = mean(0.5*maha + sum log diag) + 0.5*D*LOG_2PI
        out[0] = s * (1.0f / (float)NGROUPS) + 0.5f * 3.0f * LOG_2PI;
    }
}

extern "C" void kernel_launch(void* const* d_in, const int* in_sizes, int n_in,
                              void* d_out, int out_size, void* d_ws, size_t ws_size,
                              hipStream_t stream)
{
    const float* yt = (const float*)d_in[0];  // y_true        (B,S,J,D)
    const float* yp = (const float*)d_in[1];  // y_pred_mean   (B,S,J,D)
    const float* Lm = (const float*)d_in[2];  // pred_cholesky (B,S,J,D,D)
    float* out      = (float*)d_out;          // scalar mean
    float* partial  = (float*)d_ws;           // GRID floats (64 KB) of scratch

    nll_main<<<GRID, BLOCK, 0, stream>>>(yt, yp, Lm, partial);
    nll_reduce<<<1, 1024, 0, stream>>>(partial, out);
}